// Round 8
// baseline (134.227 us; speedup 1.0000x reference)
//
#include <hip/hip_runtime.h>
#include <hip/hip_bf16.h>
#include <math.h>

#define BB 4
#define SS 4096
#define DD 64
#define KSPLIT 4      // pb k-splits
#define QSPLIT 16     // pa q-splits

typedef __attribute__((ext_vector_type(8))) short short8;
typedef __attribute__((ext_vector_type(4))) float f32x4;
typedef __attribute__((ext_vector_type(2))) unsigned int u32x2;
typedef unsigned int u32;
typedef unsigned short ushort_t;

#define MFMA16(a,b,c) __builtin_amdgcn_mfma_f32_16x16x32_bf16((a),(b),(c),0,0,0)
// exp(s/64) == exp2(s * C2SC)
#define C2SC 0.022542110700140054f

// Raw barrier: __syncthreads() would drain vmcnt to 0 and kill the prefetch.
#define BAR() do { asm volatile("" ::: "memory"); \
                   __builtin_amdgcn_s_barrier();  \
                   asm volatile("" ::: "memory"); } while (0)
#define WAIT_VM(N)  asm volatile("s_waitcnt vmcnt(" #N ")" ::: "memory")

union Pk8 { short8 s8; u32 u[4]; u32x2 h[2]; };

static __device__ __forceinline__ unsigned short f2bf(float f) {
  union { float f; u32 u; } x; x.f = f;
  u32 r = (x.u + 0x7FFFu + ((x.u >> 16) & 1u)) >> 16;
  return (unsigned short)r;
}

// compiler lowers to v_cvt_pk_bf16_f32
static __device__ __forceinline__ u32 pk2(float a, float b) {
  __hip_bfloat16 lo = __float2bfloat16(a);
  __hip_bfloat16 hi = __float2bfloat16(b);
  unsigned short ls, hs;
  __builtin_memcpy(&ls, &lo, 2); __builtin_memcpy(&hs, &hi, 2);
  return (u32)ls | ((u32)hs << 16);
}

static __device__ __forceinline__ void gload16(const void* g, void* l) {
  __builtin_amdgcn_global_load_lds((const __attribute__((address_space(1))) u32*)g,
                                   (__attribute__((address_space(3))) u32*)l, 16, 0, 0);
}

// ---------------- P0: convert Q,K -> bf16; zero out0 and z2
__global__ __launch_bounds__(256) void p0_convert(
    const float* __restrict__ q, const float* __restrict__ k,
    ushort_t* __restrict__ QB, ushort_t* __restrict__ KB,
    float* __restrict__ out0, float* __restrict__ z2)
{
  const size_t i = (size_t)blockIdx.x * 256 + threadIdx.x;  // over BB*SS*DD/4
  float4 a = ((const float4*)q)[i];
  float4 c = ((const float4*)k)[i];
  ((ushort4*)QB)[i] = make_ushort4(f2bf(a.x), f2bf(a.y), f2bf(a.z), f2bf(a.w));
  ((ushort4*)KB)[i] = make_ushort4(f2bf(c.x), f2bf(c.y), f2bf(c.z), f2bf(c.w));
  ((float4*)out0)[i] = make_float4(0.f, 0.f, 0.f, 0.f);
  if (blockIdx.x == 0) z2[threadIdx.x] = 0.f;
}

// ============ PA: Z[k] partial = sum_{q in chunk} exp(s_qk) ============
// grid (SS/128, QSPLIT, BB), 256 thr. Wave w owns k rows 32w..32w+31 (K in regs);
// Q tiles staged via gload_lds, double-buffered, counted vmcnt.
__global__ __launch_bounds__(256, 6) void pa_colsum(
    const ushort_t* __restrict__ QB, const ushort_t* __restrict__ KB,
    float* __restrict__ Zp)
{
  const int kb0 = blockIdx.x * 128;
  const int qch = blockIdx.y;
  const int b   = blockIdx.z;
  const int t = threadIdx.x, w = t >> 6, lane = t & 63;
  const int g = lane >> 4, r15 = lane & 15;
  const int QCH = SS / QSPLIT;         // 256
  const int NT = QCH / 64;             // 4

  __shared__ alignas(16) char qbuf[2][64*128];   // 16 KB

  short8 ak[2][2];
#pragma unroll
  for (int s = 0; s < 2; ++s)
#pragma unroll
    for (int dh = 0; dh < 2; ++dh)
      ak[s][dh] = *(const short8*)(KB + ((size_t)b*SS + kb0 + 32*w + 16*s + r15)*DD + 32*dh + 8*g);

  const int q0g = qch * QCH;
#define PA_STAGE(tt, buf) do {                                              \
    _Pragma("unroll")                                                       \
    for (int j = 0; j < 2; ++j) {                                           \
      const int row = 16*w + 8*j + (lane >> 3);                             \
      const char* gsrc = (const char*)(QB + ((size_t)b*SS + q0g + (tt)*64 + row)*DD) \
                         + 16*((lane & 7) ^ (row & 7));                     \
      gload16(gsrc, qbuf[buf] + (16*w + 8*j)*128);                          \
    }                                                                       \
  } while (0)

  PA_STAGE(0, 0);

  float z[8];
#pragma unroll
  for (int i = 0; i < 8; ++i) z[i] = 0.f;

#pragma unroll 1
  for (int tt = 0; tt < NT; ++tt) {
    if (tt < NT-1) {
      PA_STAGE(tt+1, (tt+1)&1);
      WAIT_VM(2);
    } else {
      WAIT_VM(0);
    }
    BAR();
    const char* qb = qbuf[tt & 1];
#pragma unroll
    for (int qt = 0; qt < 4; ++qt) {
      const int qrow = 16*qt + r15;
      const char* base = qb + qrow*128;
      short8 bq0 = *(const short8*)(base + 16*((g    ) ^ (qrow & 7)));
      short8 bq1 = *(const short8*)(base + 16*((4 + g) ^ (qrow & 7)));
#pragma unroll
      for (int s = 0; s < 2; ++s) {
        f32x4 a = {0.f,0.f,0.f,0.f};
        a = MFMA16(ak[s][0], bq0, a);
        a = MFMA16(ak[s][1], bq1, a);
        z[4*s+0] += exp2f(a[0]*C2SC); z[4*s+1] += exp2f(a[1]*C2SC);
        z[4*s+2] += exp2f(a[2]*C2SC); z[4*s+3] += exp2f(a[3]*C2SC);
      }
    }
    BAR();
  }
#undef PA_STAGE

#pragma unroll
  for (int m = 1; m < 16; m <<= 1)
#pragma unroll
    for (int i = 0; i < 8; ++i) z[i] += __shfl_xor(z[i], m);
  if (r15 == 0) {
#pragma unroll
    for (int s = 0; s < 2; ++s)
#pragma unroll
      for (int r = 0; r < 4; ++r)
        Zp[((size_t)qch*BB + b)*SS + kb0 + 32*w + 16*s + 4*g + r] = z[4*s+r];
  }
}

// ---------------- P2: VT[b][d][s] = bf16( V[b][s][d] / Z[s] )
__global__ __launch_bounds__(256) void p2_vt(
    const float* __restrict__ v, const float* __restrict__ Zp,
    ushort_t* __restrict__ VT)
{
  const int k0 = blockIdx.x * 64;
  const int b  = blockIdx.y;
  const int t = threadIdx.x;
  __shared__ float vs[64][65];
  __shared__ float izs[64];
  {
    const int row = t >> 2, cq = (t & 3) * 16;
    const float* src = v + ((size_t)b*SS + k0 + row)*DD + cq;
#pragma unroll
    for (int i = 0; i < 4; ++i) {
      float4 x = ((const float4*)src)[i];
      vs[row][cq + 4*i + 0] = x.x; vs[row][cq + 4*i + 1] = x.y;
      vs[row][cq + 4*i + 2] = x.z; vs[row][cq + 4*i + 3] = x.w;
    }
  }
  if (t < 64) {
    float z = 0.f;
#pragma unroll
    for (int c = 0; c < QSPLIT; ++c)
      z += Zp[((size_t)c*BB + b)*SS + k0 + t];
    izs[t] = 1.0f / z;
  }
  __syncthreads();
  const int d = t >> 2, ks = (t & 3) * 16;
  u32* dst = (u32*)VT + (((size_t)b*DD + d)*SS + k0 + ks)/2;
#pragma unroll
  for (int i = 0; i < 8; ++i) {
    float a0 = vs[ks + 2*i    ][d] * izs[ks + 2*i    ];
    float a1 = vs[ks + 2*i + 1][d] * izs[ks + 2*i + 1];
    dst[i] = (u32)f2bf(a0) | ((u32)f2bf(a1) << 16);
  }
}

// ============ PB: attn contribution = exp(QK^T/64) * VT over this block's k-quarter ============
// 512 thr, grid (SS/128, KSPLIT, BB) = 512 blocks (exactly 2/CU, 16 waves/CU).
// Two 64-q halves (h = wave>>2); within a half, wave w owns k-slices 16w / 64+16w
// of each 128-k step. Q in regs; P never leaves registers (pi-paired PV).
// MODE 0: atomicAdd into out0.  MODE 1: plain store to partials[ky].
template<int MODE>
__global__ __launch_bounds__(512, 4) void pb_attn(
    const ushort_t* __restrict__ QB, const ushort_t* __restrict__ KB,
    const ushort_t* __restrict__ VT, float* __restrict__ outp)
{
  const int q0 = blockIdx.x * 128;
  const int ky = blockIdx.y;
  const int kbase = ky * (SS / KSPLIT);
  const int b  = blockIdx.z;
  const int t = threadIdx.x, w8 = t >> 6, lane = t & 63;
  const int w = w8 & 3, h = w8 >> 2;
  const int g = lane >> 4, r15 = lane & 15;
  const int qbase = q0 + 64*h;
  const int NT = SS / KSPLIT / 128;    // 8

  __shared__ alignas(16) char smem[65536];   // [2][16KB K] + [2][16KB V]
  char* kbuf = smem;            // + buf*16384
  char* vbuf = smem + 32768;    // + buf*16384

  // Q fragments in registers: this half's 64 q rows
  short8 aq[4][2];
#pragma unroll
  for (int qt = 0; qt < 4; ++qt)
#pragma unroll
    for (int dh = 0; dh < 2; ++dh)
      aq[qt][dh] = *(const short8*)(QB + ((size_t)b*SS + qbase + 16*qt + r15)*DD + 32*dh + 8*g);

  f32x4 acc[4][4];
#pragma unroll
  for (int qt = 0; qt < 4; ++qt)
#pragma unroll
    for (int dt = 0; dt < 4; ++dt) acc[qt][dt] = (f32x4){0.f,0.f,0.f,0.f};

  // stage tile kt into buf: K 128 rows x 128B + V 64 rows x 256B; 8 waves share.
#define PB_STAGE(kt, buf) do {                                               \
    const int kc = kbase + (kt)*128;                                         \
    _Pragma("unroll")                                                        \
    for (int j = 0; j < 2; ++j) {                                            \
      const int row = 16*w8 + 8*j + (lane >> 3);                             \
      const char* gk = (const char*)(KB + ((size_t)b*SS + kc + row)*DD)      \
                       + 16*((lane & 7) ^ (row & 7));                        \
      gload16(gk, kbuf + (buf)*16384 + (16*w8 + 8*j)*128);                   \
    }                                                                        \
    _Pragma("unroll")                                                        \
    for (int j = 0; j < 2; ++j) {                                            \
      const int row = 8*w8 + 4*j + (lane >> 4);                              \
      const char* gv = (const char*)(VT + ((size_t)b*DD + row)*SS + kc)      \
                       + 16*((lane & 15) ^ (row & 15));                      \
      gload16(gv, vbuf + (buf)*16384 + (8*w8 + 4*j)*256);                    \
    }                                                                        \
  } while (0)

  PB_STAGE(0, 0);

#pragma unroll 1
  for (int kt = 0; kt < NT; ++kt) {
    if (kt < NT-1) {
      PB_STAGE(kt+1, (kt+1)&1);
      WAIT_VM(4);
    } else {
      WAIT_VM(0);
    }
    BAR();
    const char* kb = kbuf + (kt&1)*16384;
    const char* vb = vbuf + (kt&1)*16384;

    // QK^T (swapped: A=K, B=Q); P packed into registers
    u32 pk[2][4][2];
#pragma unroll
    for (int s = 0; s < 2; ++s) {
      const int rowA = 64*s + 16*w + r15;
      const char* base = kb + rowA*128;
      short8 ka0 = *(const short8*)(base + 16*((g    ) ^ (rowA & 7)));
      short8 ka1 = *(const short8*)(base + 16*((4 + g) ^ (rowA & 7)));
#pragma unroll
      for (int qt = 0; qt < 4; ++qt) {
        f32x4 a = {0.f,0.f,0.f,0.f};
        a = MFMA16(ka0, aq[qt][0], a);
        a = MFMA16(ka1, aq[qt][1], a);
        pk[s][qt][0] = pk2(exp2f(a[0]*C2SC), exp2f(a[1]*C2SC));
        pk[s][qt][1] = pk2(exp2f(a[2]*C2SC), exp2f(a[3]*C2SC));
      }
    }
    // V fragments (pi-paired k ordering)
    short8 bv[4];
#pragma unroll
    for (int dt = 0; dt < 4; ++dt) {
      const int vrow = 16*dt + r15;
      Pk8 u;
      u.h[0] = *(const u32x2*)(vb + vrow*256 + 16*((    2*w + (g>>1)) ^ r15) + 8*(g&1));
      u.h[1] = *(const u32x2*)(vb + vrow*256 + 16*((8 + 2*w + (g>>1)) ^ r15) + 8*(g&1));
      bv[dt] = u.s8;
    }
    // PV: A = P (registers), kdim pairs subtiles {s=0, s=1}
#pragma unroll
    for (int qt = 0; qt < 4; ++qt) {
      Pk8 ap;
      ap.u[0] = pk[0][qt][0]; ap.u[1] = pk[0][qt][1];
      ap.u[2] = pk[1][qt][0]; ap.u[3] = pk[1][qt][1];
#pragma unroll
      for (int dt = 0; dt < 4; ++dt)
        acc[qt][dt] = MFMA16(ap.s8, bv[dt], acc[qt][dt]);
    }
    BAR();
  }
#undef PB_STAGE

  // per-half cross-wave reduction in this half's 32KB region
  f32x4* red = (f32x4*)(smem + h*32768);   // 2048 f32x4
  if (w == 1) {
#pragma unroll
    for (int qt = 0; qt < 4; ++qt)
#pragma unroll
      for (int dt = 0; dt < 4; ++dt) red[(qt*4+dt)*64 + lane] = acc[qt][dt];
  }
  if (w == 3) {
#pragma unroll
    for (int qt = 0; qt < 4; ++qt)
#pragma unroll
      for (int dt = 0; dt < 4; ++dt) red[1024 + (qt*4+dt)*64 + lane] = acc[qt][dt];
  }
  __syncthreads();
  if (w == 0) {
#pragma unroll
    for (int qt = 0; qt < 4; ++qt)
#pragma unroll
      for (int dt = 0; dt < 4; ++dt) acc[qt][dt] += red[(qt*4+dt)*64 + lane];
  }
  if (w == 2) {
#pragma unroll
    for (int qt = 0; qt < 4; ++qt)
#pragma unroll
      for (int dt = 0; dt < 4; ++dt) acc[qt][dt] += red[1024 + (qt*4+dt)*64 + lane];
  }
  __syncthreads();
  if (w == 2) {
#pragma unroll
    for (int qt = 0; qt < 4; ++qt)
#pragma unroll
      for (int dt = 0; dt < 4; ++dt) red[(qt*4+dt)*64 + lane] = acc[qt][dt];
  }
  __syncthreads();
  if (w == 0) {
    float* dst = (MODE == 0) ? outp : outp + (size_t)ky * BB * SS * DD;
#pragma unroll
    for (int qt = 0; qt < 4; ++qt)
#pragma unroll
      for (int dt = 0; dt < 4; ++dt) {
        f32x4 s = acc[qt][dt] + red[(qt*4+dt)*64 + lane];
#pragma unroll
        for (int rr = 0; rr < 4; ++rr) {
          const size_t idx = ((size_t)b*SS + qbase + 16*qt + 4*g + rr)*DD + 16*dt + r15;
          if (MODE == 0) atomicAdd(&outp[idx], s[rr]);
          else           dst[idx] = s[rr];
        }
      }
  }
}

// ---------------- K4F (atomic fallback): colsum of exp(attn) -> z2
__global__ __launch_bounds__(256) void k4f(
    const float* __restrict__ attn, float* __restrict__ z2)
{
  const int b = blockIdx.x;
  const int q0 = blockIdx.y * 32;
  const int t = threadIdx.x;
  const int d = t & 63, rg = t >> 6;
  float ze = 0.f;
#pragma unroll
  for (int i = 0; i < 8; ++i) {
    float a = attn[((size_t)b*SS + q0 + 4*i + rg)*DD + d];
    ze += __expf(a);
  }
  __shared__ float red[4][64];
  red[rg][d] = ze;
  __syncthreads();
  if (t < 64)
    atomicAdd(&z2[b*DD + t], red[0][t] + red[1][t] + red[2][t] + red[3][t]);
}

// ---------------- K5 (partials path): attn = sum partials -> out0, + exp colsum -> z2
__global__ __launch_bounds__(256) void k5_comb(
    const float* __restrict__ parts, float* __restrict__ out0, float* __restrict__ z2)
{
  const int b = blockIdx.x;
  const int q0 = blockIdx.y * 32;
  const int t = threadIdx.x;
  const int d = t & 63, rg = t >> 6;
  const size_t N = (size_t)BB * SS * DD;
  float ze = 0.f;
#pragma unroll
  for (int i = 0; i < 8; ++i) {
    const size_t idx = ((size_t)b*SS + q0 + 4*i + rg)*DD + d;
    float a = parts[idx] + parts[N + idx] + parts[2*N + idx] + parts[3*N + idx];
    out0[idx] = a;
    ze += __expf(a);
  }
  __shared__ float red[4][64];
  red[rg][d] = ze;
  __syncthreads();
  if (t < 64)
    atomicAdd(&z2[b*DD + t], red[0][t] + red[1][t] + red[2][t] + red[3][t]);
}

// ---------------- K6: attn_w = exp(attn) / z2
__global__ __launch_bounds__(256) void k6w(
    const float* __restrict__ attn, const float* __restrict__ z2,
    float* __restrict__ out1)
{
  const size_t i = (size_t)blockIdx.x * 256 + threadIdx.x;
  const int b = (int)(i >> 18);        // SS*DD = 262144
  const int d = (int)(i & 63);
  out1[i] = __expf(attn[i]) / z2[b*DD + d];
}

extern "C" void kernel_launch(void* const* d_in, const int* in_sizes, int n_in,
                              void* d_out, int out_size, void* d_ws, size_t ws_size,
                              hipStream_t stream) {
  const float* q = (const float*)d_in[0];
  const float* k = (const float*)d_in[1];
  const float* v = (const float*)d_in[2];
  float* out0 = (float*)d_out;
  float* out1 = out0 + (size_t)BB * SS * DD;

  // bf16 Q/K scratch lives in the out1 region (overwritten by k6w at the end).
  ushort_t* QB = (ushort_t*)out1;                 // 2 MB
  ushort_t* KB = QB + (size_t)BB * SS * DD;       // 2 MB

  char* ws = (char*)d_ws;
  ushort_t* VT = (ushort_t*)ws;                               // 2 MB bf16
  float* Zp = (float*)(ws + (size_t)BB*DD*SS*2);              // 1 MB
  float* z2 = Zp + (size_t)QSPLIT * BB * SS;                  // 1 KB
  float* parts = z2 + 256;                                    // 16 MB (if available)

  const size_t need = (size_t)BB*DD*SS*2 + (size_t)QSPLIT*BB*SS*4 + 1024
                    + (size_t)KSPLIT*BB*SS*DD*4;
  const bool use_parts = (ws_size >= need);

  hipLaunchKernelGGL(p0_convert, dim3(BB*SS*DD/4/256), dim3(256), 0, stream, q, k, QB, KB, out0, z2);
  hipLaunchKernelGGL(pa_colsum, dim3(SS/128, QSPLIT, BB), dim3(256), 0, stream, QB, KB, Zp);
  hipLaunchKernelGGL(p2_vt, dim3(SS/64, BB), dim3(256), 0, stream, v, Zp, VT);
  if (use_parts) {
    pb_attn<1><<<dim3(SS/128, KSPLIT, BB), dim3(512), 0, stream>>>(QB, KB, VT, parts);
    hipLaunchKernelGGL(k5_comb, dim3(BB, SS/32), dim3(256), 0, stream, parts, out0, z2);
  } else {
    pb_attn<0><<<dim3(SS/128, KSPLIT, BB), dim3(512), 0, stream>>>(QB, KB, VT, out0);
    hipLaunchKernelGGL(k4f, dim3(BB, SS/32), dim3(256), 0, stream, out0, z2);
  }
  hipLaunchKernelGGL(k6w, dim3(BB*SS*DD/256), dim3(256), 0, stream, out0, z2, out1);
}

// Round 11
// 87.942 us; speedup vs baseline: 1.5263x; 1.5263x over previous
//
#include <hip/hip_runtime.h>
#include <hip/hip_bf16.h>
#include <math.h>

#define BB 4
#define SS 4096
#define DD 64
#define KSPLIT 4      // pb k-splits
#define QSPLIT 16     // pa q-splits

typedef __attribute__((ext_vector_type(8))) short short8;
typedef __attribute__((ext_vector_type(4))) float f32x4;
typedef __attribute__((ext_vector_type(2))) unsigned int u32x2;
typedef unsigned int u32;
typedef unsigned short ushort_t;

#define MFMA32(a,b,c) __builtin_amdgcn_mfma_f32_16x16x32_bf16((a),(b),(c),0,0,0)
// exp(s/64) == exp2(s * C2SC); Q is PRESCALED by C2SC in p0, so kernels use exp2 directly.
#define C2SC 0.022542110700140054f

// Raw barrier: __syncthreads() would drain vmcnt to 0 and kill the prefetch.
#define BAR() do { asm volatile("" ::: "memory"); \
                   __builtin_amdgcn_s_barrier();  \
                   asm volatile("" ::: "memory"); } while (0)
#define WAIT_VM(N)  asm volatile("s_waitcnt vmcnt(" #N ")" ::: "memory")
// Exit-barrier discipline (rule #18): retire ALL DS ops and pin the schedule
// BEFORE the raw barrier, else in-flight ds_reads can cross the barrier and
// race the next tile's global_load_lds DMA writes.
#define DS_FENCE() do { asm volatile("s_waitcnt lgkmcnt(0)" ::: "memory"); \
                        __builtin_amdgcn_sched_barrier(0); } while (0)

union Pk8 { short8 s8; u32 u[4]; u32x2 h[2]; };

static __device__ __forceinline__ unsigned short f2bf(float f) {
  union { float f; u32 u; } x; x.f = f;
  u32 r = (x.u + 0x7FFFu + ((x.u >> 16) & 1u)) >> 16;
  return (unsigned short)r;
}

// compiler lowers to v_cvt_pk_bf16_f32
static __device__ __forceinline__ u32 pk2(float a, float b) {
  __hip_bfloat16 lo = __float2bfloat16(a);
  __hip_bfloat16 hi = __float2bfloat16(b);
  unsigned short ls, hs;
  __builtin_memcpy(&ls, &lo, 2); __builtin_memcpy(&hs, &hi, 2);
  return (u32)ls | ((u32)hs << 16);
}

static __device__ __forceinline__ void gload16(const void* g, void* l) {
  __builtin_amdgcn_global_load_lds((const __attribute__((address_space(1))) u32*)g,
                                   (__attribute__((address_space(3))) u32*)l, 16, 0, 0);
}

// ---------------- P0: convert Q (prescaled by C2SC), K -> bf16; zero out0 and z2
__global__ __launch_bounds__(256) void p0_convert(
    const float* __restrict__ q, const float* __restrict__ k,
    ushort_t* __restrict__ QB, ushort_t* __restrict__ KB,
    float* __restrict__ out0, float* __restrict__ z2)
{
  const size_t i = (size_t)blockIdx.x * 256 + threadIdx.x;  // over BB*SS*DD/4
  float4 a = ((const float4*)q)[i];
  float4 c = ((const float4*)k)[i];
  ((ushort4*)QB)[i] = make_ushort4(f2bf(a.x*C2SC), f2bf(a.y*C2SC), f2bf(a.z*C2SC), f2bf(a.w*C2SC));
  ((ushort4*)KB)[i] = make_ushort4(f2bf(c.x), f2bf(c.y), f2bf(c.z), f2bf(c.w));
  ((float4*)out0)[i] = make_float4(0.f, 0.f, 0.f, 0.f);
  if (blockIdx.x == 0) z2[threadIdx.x] = 0.f;
}

// ============ PA: Z[k] partial = sum_{q in chunk} exp2(s') ============
// grid (SS/128, QSPLIT, BB), 256 thr. Wave w owns k rows 32w..32w+31 (K in regs);
// Q tiles staged via gload_lds, double-buffered, counted vmcnt.
__global__ __launch_bounds__(256) void pa_colsum(
    const ushort_t* __restrict__ QB, const ushort_t* __restrict__ KB,
    float* __restrict__ Zp)
{
  const int kb0 = blockIdx.x * 128;
  const int qch = blockIdx.y;
  const int b   = blockIdx.z;
  const int t = threadIdx.x, w = t >> 6, lane = t & 63;
  const int g = lane >> 4, r15 = lane & 15;
  const int QCH = SS / QSPLIT;         // 256
  const int NT = QCH / 64;             // 4

  __shared__ alignas(16) char qbuf[2][64*128];   // 16 KB

  short8 ak[2][2];
#pragma unroll
  for (int s = 0; s < 2; ++s)
#pragma unroll
    for (int dh = 0; dh < 2; ++dh)
      ak[s][dh] = *(const short8*)(KB + ((size_t)b*SS + kb0 + 32*w + 16*s + r15)*DD + 32*dh + 8*g);

  const int q0g = qch * QCH;
#define PA_STAGE(tt, buf) do {                                              \
    _Pragma("unroll")                                                       \
    for (int j = 0; j < 2; ++j) {                                           \
      const int row = 16*w + 8*j + (lane >> 3);                             \
      const char* gsrc = (const char*)(QB + ((size_t)b*SS + q0g + (tt)*64 + row)*DD) \
                         + 16*((lane & 7) ^ (row & 7));                     \
      gload16(gsrc, qbuf[buf] + (16*w + 8*j)*128);                          \
    }                                                                       \
  } while (0)

  PA_STAGE(0, 0);

  float z[8];
#pragma unroll
  for (int i = 0; i < 8; ++i) z[i] = 0.f;

#pragma unroll 1
  for (int tt = 0; tt < NT; ++tt) {
    if (tt < NT-1) {
      PA_STAGE(tt+1, (tt+1)&1);
      WAIT_VM(2);
    } else {
      WAIT_VM(0);
    }
    BAR();
    const char* qb = qbuf[tt & 1];
#pragma unroll
    for (int qt = 0; qt < 4; ++qt) {
      const int qrow = 16*qt + r15;
      const char* base = qb + qrow*128;
      short8 bq0 = *(const short8*)(base + 16*((g    ) ^ (qrow & 7)));
      short8 bq1 = *(const short8*)(base + 16*((4 + g) ^ (qrow & 7)));
#pragma unroll
      for (int s = 0; s < 2; ++s) {
        f32x4 a = {0.f,0.f,0.f,0.f};
        a = MFMA32(ak[s][0], bq0, a);
        a = MFMA32(ak[s][1], bq1, a);
        z[4*s+0] += exp2f(a[0]); z[4*s+1] += exp2f(a[1]);
        z[4*s+2] += exp2f(a[2]); z[4*s+3] += exp2f(a[3]);
      }
    }
    DS_FENCE();
    BAR();
  }
#undef PA_STAGE

#pragma unroll
  for (int m = 1; m < 16; m <<= 1)
#pragma unroll
    for (int i = 0; i < 8; ++i) z[i] += __shfl_xor(z[i], m);
  if (r15 == 0) {
#pragma unroll
    for (int s = 0; s < 2; ++s)
#pragma unroll
      for (int r = 0; r < 4; ++r)
        Zp[((size_t)qch*BB + b)*SS + kb0 + 32*w + 16*s + 4*g + r] = z[4*s+r];
  }
}

// ---------------- P2: VT[b][d][s] = bf16( V[b][s][d] / Z[s] )
__global__ __launch_bounds__(256) void p2_vt(
    const float* __restrict__ v, const float* __restrict__ Zp,
    ushort_t* __restrict__ VT)
{
  const int k0 = blockIdx.x * 64;
  const int b  = blockIdx.y;
  const int t = threadIdx.x;
  __shared__ float vs[64][65];
  __shared__ float izs[64];
  {
    const int row = t >> 2, cq = (t & 3) * 16;
    const float* src = v + ((size_t)b*SS + k0 + row)*DD + cq;
#pragma unroll
    for (int i = 0; i < 4; ++i) {
      float4 x = ((const float4*)src)[i];
      vs[row][cq + 4*i + 0] = x.x; vs[row][cq + 4*i + 1] = x.y;
      vs[row][cq + 4*i + 2] = x.z; vs[row][cq + 4*i + 3] = x.w;
    }
  }
  if (t < 64) {
    float z = 0.f;
#pragma unroll
    for (int c = 0; c < QSPLIT; ++c)
      z += Zp[((size_t)c*BB + b)*SS + k0 + t];
    izs[t] = 1.0f / z;
  }
  __syncthreads();
  const int d = t >> 2, ks = (t & 3) * 16;
  u32* dst = (u32*)VT + (((size_t)b*DD + d)*SS + k0 + ks)/2;
#pragma unroll
  for (int i = 0; i < 8; ++i) {
    float a0 = vs[ks + 2*i    ][d] * izs[ks + 2*i    ];
    float a1 = vs[ks + 2*i + 1][d] * izs[ks + 2*i + 1];
    dst[i] = (u32)f2bf(a0) | ((u32)f2bf(a1) << 16);
  }
}

// ============ PB: attn contribution = exp2(QK'^T) * VT over this block's k-quarter ============
// grid (SS/32, KSPLIT, BB), 256 thr. Block tile: 32 q x 64 k per step (BK=64).
// Wave w: wk=w>>1 selects 32-k half, qs=w&1 selects 16-q half -> no duplication.
// Swapped QK^T gives P[k=32wk+16s+4g+rr][q=r15]; two s-subtiles pack into one
// K=32 A-frag; V B-frag gathered with the SAME per-lane k permutation ->
// P never leaves registers. 32 KB dbuf LDS, counted vmcnt(4), raw barriers.
// MODE 0: atomicAdd into out0.  MODE 1: plain store to partials[ky].
template<int MODE>
__global__ __launch_bounds__(256) void pb_attn(
    const ushort_t* __restrict__ QB, const ushort_t* __restrict__ KB,
    const ushort_t* __restrict__ VT, float* __restrict__ outp)
{
  const int qbase = blockIdx.x * 32;
  const int ky = blockIdx.y;
  const int kbase = ky * (SS / KSPLIT);
  const int b  = blockIdx.z;
  const int t = threadIdx.x, w = t >> 6, lane = t & 63;
  const int g = lane >> 4, r15 = lane & 15;
  const int wk = w >> 1, qs = w & 1;
  const int NT = SS / KSPLIT / 64;    // 16

  __shared__ alignas(16) char smem[32768];   // dbuf: [2][8KB K + 8KB V]

  // Q fragments in registers: this wave's 16 q rows
  short8 aq[2];
#pragma unroll
  for (int dh = 0; dh < 2; ++dh)
    aq[dh] = *(const short8*)(QB + ((size_t)b*SS + qbase + 16*qs + r15)*DD + 32*dh + 8*g);

  f32x4 acc[4];
#pragma unroll
  for (int dt = 0; dt < 4; ++dt) acc[dt] = (f32x4){0.f,0.f,0.f,0.f};

  // stage tile kt into buf: K 64 rows x 128B + V 64 d-rows x 128B (64 k x 2B)
#define PB_STAGE(kt, buf) do {                                               \
    const int kc = kbase + (kt)*64;                                          \
    _Pragma("unroll")                                                        \
    for (int j = 0; j < 2; ++j) {                                            \
      const int row = 16*w + 8*j + (lane >> 3);                              \
      const char* gk = (const char*)(KB + ((size_t)b*SS + kc + row)*DD)      \
                       + 16*((lane & 7) ^ (row & 7));                        \
      gload16(gk, smem + (buf)*16384 + (16*w + 8*j)*128);                    \
    }                                                                        \
    _Pragma("unroll")                                                        \
    for (int j = 0; j < 2; ++j) {                                            \
      const int row = 16*w + 8*j + (lane >> 3);                              \
      const char* gv = (const char*)(VT + ((size_t)b*DD + row)*SS + kc)      \
                       + 16*((lane & 7) ^ (row & 7));                        \
      gload16(gv, smem + (buf)*16384 + 8192 + (16*w + 8*j)*128);             \
    }                                                                        \
  } while (0)

  PB_STAGE(0, 0);

#pragma unroll 1
  for (int kt = 0; kt < NT; ++kt) {
    if (kt < NT-1) {
      PB_STAGE(kt+1, (kt+1)&1);
      WAIT_VM(4);
    } else {
      WAIT_VM(0);
    }
    BAR();
    const char* kb = smem + (kt&1)*16384;
    const char* vb = kb + 8192;

    // QK^T (swapped: A=K rows 32wk+16s.., B=Q) -> P[k=32wk+16s+4g+rr][q=r15]
    u32 pku[2][2];
#pragma unroll
    for (int s = 0; s < 2; ++s) {
      const int rowA = 32*wk + 16*s + r15;
      const char* base = kb + rowA*128;
      short8 ka0 = *(const short8*)(base + 16*((g    ) ^ (r15 & 7)));
      short8 ka1 = *(const short8*)(base + 16*((4 + g) ^ (r15 & 7)));
      f32x4 a = {0.f,0.f,0.f,0.f};
      a = MFMA32(ka0, aq[0], a);
      a = MFMA32(ka1, aq[1], a);
      pku[s][0] = pk2(exp2f(a[0]), exp2f(a[1]));
      pku[s][1] = pk2(exp2f(a[2]), exp2f(a[3]));
    }
    Pk8 ap;
    ap.u[0] = pku[0][0]; ap.u[1] = pku[0][1];
    ap.u[2] = pku[1][0]; ap.u[3] = pku[1][1];
    // lane j-order k-list: {32wk+4g+0..3, 32wk+16+4g+0..3}

    // V B-frags with the SAME k permutation: bytes 64wk+8g (+32 for s=1)
    short8 bv[4];
#pragma unroll
    for (int dt = 0; dt < 4; ++dt) {
      const int vrow = 16*dt + r15;
      Pk8 u;
      u.h[0] = *(const u32x2*)(vb + vrow*128 + 16*((4*wk     + (g>>1)) ^ (r15 & 7)) + 8*(g&1));
      u.h[1] = *(const u32x2*)(vb + vrow*128 + 16*((4*wk + 2 + (g>>1)) ^ (r15 & 7)) + 8*(g&1));
      bv[dt] = u.s8;
    }
    // PV: A = P (registers), K=32
#pragma unroll
    for (int dt = 0; dt < 4; ++dt)
      acc[dt] = MFMA32(ap.s8, bv[dt], acc[dt]);
    DS_FENCE();
    BAR();
  }
#undef PB_STAGE

  // reduce the two wk halves (same qs) through LDS, then wk==0 outputs
  f32x4* red = (f32x4*)smem;   // [2 qs][4 dt][64 lanes] = 8 KB
  if (wk == 1) {
#pragma unroll
    for (int dt = 0; dt < 4; ++dt) red[(qs*4 + dt)*64 + lane] = acc[dt];
  }
  __syncthreads();
  if (wk == 0) {
    float* dst = (MODE == 0) ? outp : outp + (size_t)ky * BB * SS * DD;
#pragma unroll
    for (int dt = 0; dt < 4; ++dt) {
      f32x4 s = acc[dt] + red[(qs*4 + dt)*64 + lane];
#pragma unroll
      for (int rr = 0; rr < 4; ++rr) {
        const size_t idx = ((size_t)b*SS + qbase + 16*qs + 4*g + rr)*DD + 16*dt + r15;
        if (MODE == 0) atomicAdd(&outp[idx], s[rr]);
        else           dst[idx] = s[rr];
      }
    }
  }
}

// ---------------- K4F (atomic fallback): colsum of exp(attn) -> z2
__global__ __launch_bounds__(256) void k4f(
    const float* __restrict__ attn, float* __restrict__ z2)
{
  const int b = blockIdx.x;
  const int q0 = blockIdx.y * 32;
  const int t = threadIdx.x;
  const int d = t & 63, rg = t >> 6;
  float ze = 0.f;
#pragma unroll
  for (int i = 0; i < 8; ++i) {
    float a = attn[((size_t)b*SS + q0 + 4*i + rg)*DD + d];
    ze += __expf(a);
  }
  __shared__ float red[4][64];
  red[rg][d] = ze;
  __syncthreads();
  if (t < 64)
    atomicAdd(&z2[b*DD + t], red[0][t] + red[1][t] + red[2][t] + red[3][t]);
}

// ---------------- K5 (partials path): attn = sum partials -> out0, + exp colsum -> z2
__global__ __launch_bounds__(256) void k5_comb(
    const float* __restrict__ parts, float* __restrict__ out0, float* __restrict__ z2)
{
  const int b = blockIdx.x;
  const int q0 = blockIdx.y * 32;
  const int t = threadIdx.x;
  const int d = t & 63, rg = t >> 6;
  const size_t N = (size_t)BB * SS * DD;
  float ze = 0.f;
#pragma unroll
  for (int i = 0; i < 8; ++i) {
    const size_t idx = ((size_t)b*SS + q0 + 4*i + rg)*DD + d;
    float a = parts[idx] + parts[N + idx] + parts[2*N + idx] + parts[3*N + idx];
    out0[idx] = a;
    ze += __expf(a);
  }
  __shared__ float red[4][64];
  red[rg][d] = ze;
  __syncthreads();
  if (t < 64)
    atomicAdd(&z2[b*DD + t], red[0][t] + red[1][t] + red[2][t] + red[3][t]);
}

// ---------------- K6: attn_w = exp(attn) / z2
__global__ __launch_bounds__(256) void k6w(
    const float* __restrict__ attn, const float* __restrict__ z2,
    float* __restrict__ out1)
{
  const size_t i = (size_t)blockIdx.x * 256 + threadIdx.x;
  const int b = (int)(i >> 18);        // SS*DD = 262144
  const int d = (int)(i & 63);
  out1[i] = __expf(attn[i]) / z2[b*DD + d];
}

extern "C" void kernel_launch(void* const* d_in, const int* in_sizes, int n_in,
                              void* d_out, int out_size, void* d_ws, size_t ws_size,
                              hipStream_t stream) {
  const float* q = (const float*)d_in[0];
  const float* k = (const float*)d_in[1];
  const float* v = (const float*)d_in[2];
  float* out0 = (float*)d_out;
  float* out1 = out0 + (size_t)BB * SS * DD;

  // bf16 Q/K scratch lives in the out1 region (overwritten by k6w at the end).
  ushort_t* QB = (ushort_t*)out1;                 // 2 MB
  ushort_t* KB = QB + (size_t)BB * SS * DD;       // 2 MB

  char* ws = (char*)d_ws;
  ushort_t* VT = (ushort_t*)ws;                               // 2 MB bf16
  float* Zp = (float*)(ws + (size_t)BB*DD*SS*2);              // 1 MB
  float* z2 = Zp + (size_t)QSPLIT * BB * SS;                  // 1 KB
  float* parts = z2 + 256;                                    // 16 MB (if available)

  const size_t need = (size_t)BB*DD*SS*2 + (size_t)QSPLIT*BB*SS*4 + 1024
                    + (size_t)KSPLIT*BB*SS*DD*4;
  const bool use_parts = (ws_size >= need);

  hipLaunchKernelGGL(p0_convert, dim3(BB*SS*DD/4/256), dim3(256), 0, stream, q, k, QB, KB, out0, z2);
  hipLaunchKernelGGL(pa_colsum, dim3(SS/128, QSPLIT, BB), dim3(256), 0, stream, QB, KB, Zp);
  hipLaunchKernelGGL(p2_vt, dim3(SS/64, BB), dim3(256), 0, stream, v, Zp, VT);
  if (use_parts) {
    pb_attn<1><<<dim3(SS/32, KSPLIT, BB), dim3(256), 0, stream>>>(QB, KB, VT, parts);
    hipLaunchKernelGGL(k5_comb, dim3(BB, SS/32), dim3(256), 0, stream, parts, out0, z2);
  } else {
    pb_attn<0><<<dim3(SS/32, KSPLIT, BB), dim3(256), 0, stream>>>(QB, KB, VT, out0);
    hipLaunchKernelGGL(k4f, dim3(BB, SS/32), dim3(256), 0, stream, out0, z2);
  }
  hipLaunchKernelGGL(k6w, dim3(BB*SS*DD/256), dim3(256), 0, stream, out0, z2, out1);
}

// Round 12
// 85.352 us; speedup vs baseline: 1.5726x; 1.0303x over previous
//
#include <hip/hip_runtime.h>
#include <hip/hip_bf16.h>
#include <math.h>

#define BB 4
#define SS 4096
#define DD 64
#define KSPLIT 4      // pb k-splits
#define QSPLIT 4      // pa q-splits

typedef __attribute__((ext_vector_type(8))) short short8;
typedef __attribute__((ext_vector_type(4))) float f32x4;
typedef __attribute__((ext_vector_type(2))) unsigned int u32x2;
typedef unsigned int u32;
typedef unsigned short ushort_t;

#define MFMA32(a,b,c) __builtin_amdgcn_mfma_f32_16x16x32_bf16((a),(b),(c),0,0,0)
// exp(s/64) == exp2(s * C2SC); Q is PRESCALED by C2SC in p0, so kernels use exp2 directly.
#define C2SC 0.022542110700140054f

// Raw barrier: __syncthreads() would drain vmcnt to 0 and kill the prefetch.
#define BAR() do { asm volatile("" ::: "memory"); \
                   __builtin_amdgcn_s_barrier();  \
                   asm volatile("" ::: "memory"); } while (0)
#define WAIT_VM(N)  asm volatile("s_waitcnt vmcnt(" #N ")" ::: "memory")
// Exit-barrier discipline (rule #18): retire ALL DS ops and pin the schedule
// BEFORE the raw barrier, else in-flight ds_reads can cross the barrier and
// race the next tile's global_load_lds DMA writes.
#define DS_FENCE() do { asm volatile("s_waitcnt lgkmcnt(0)" ::: "memory"); \
                        __builtin_amdgcn_sched_barrier(0); } while (0)

union Pk8 { short8 s8; u32 u[4]; u32x2 h[2]; };

static __device__ __forceinline__ unsigned short f2bf(float f) {
  union { float f; u32 u; } x; x.f = f;
  u32 r = (x.u + 0x7FFFu + ((x.u >> 16) & 1u)) >> 16;
  return (unsigned short)r;
}

// compiler lowers to v_cvt_pk_bf16_f32
static __device__ __forceinline__ u32 pk2(float a, float b) {
  __hip_bfloat16 lo = __float2bfloat16(a);
  __hip_bfloat16 hi = __float2bfloat16(b);
  unsigned short ls, hs;
  __builtin_memcpy(&ls, &lo, 2); __builtin_memcpy(&hs, &hs, 0);
  __builtin_memcpy(&hs, &hi, 2);
  return (u32)ls | ((u32)hs << 16);
}

static __device__ __forceinline__ void gload16(const void* g, void* l) {
  __builtin_amdgcn_global_load_lds((const __attribute__((address_space(1))) u32*)g,
                                   (__attribute__((address_space(3))) u32*)l, 16, 0, 0);
}

// ---------------- P0: convert Q (prescaled by C2SC), K -> bf16; zero out0 and z2
__global__ __launch_bounds__(256) void p0_convert(
    const float* __restrict__ q, const float* __restrict__ k,
    ushort_t* __restrict__ QB, ushort_t* __restrict__ KB,
    float* __restrict__ out0, float* __restrict__ z2)
{
  const size_t i = (size_t)blockIdx.x * 256 + threadIdx.x;  // over BB*SS*DD/4
  float4 a = ((const float4*)q)[i];
  float4 c = ((const float4*)k)[i];
  ((ushort4*)QB)[i] = make_ushort4(f2bf(a.x*C2SC), f2bf(a.y*C2SC), f2bf(a.z*C2SC), f2bf(a.w*C2SC));
  ((ushort4*)KB)[i] = make_ushort4(f2bf(c.x), f2bf(c.y), f2bf(c.z), f2bf(c.w));
  ((float4*)out0)[i] = make_float4(0.f, 0.f, 0.f, 0.f);
  if (blockIdx.x == 0) z2[threadIdx.x] = 0.f;
}

// ============ PA: Z[k] partial = sum_{q in chunk} exp2(s') ============
// grid (SS/128, QSPLIT, BB), 256 thr. Wave w owns k rows 32w..32w+31 (K in regs);
// Q tiles staged via gload_lds, double-buffered, counted vmcnt. NT=16 amortizes
// the scattered K-register load.
__global__ __launch_bounds__(256) void pa_colsum(
    const ushort_t* __restrict__ QB, const ushort_t* __restrict__ KB,
    float* __restrict__ Zp)
{
  const int kb0 = blockIdx.x * 128;
  const int qch = blockIdx.y;
  const int b   = blockIdx.z;
  const int t = threadIdx.x, w = t >> 6, lane = t & 63;
  const int g = lane >> 4, r15 = lane & 15;
  const int QCH = SS / QSPLIT;         // 1024
  const int NT = QCH / 64;             // 16

  __shared__ alignas(16) char qbuf[2][64*128];   // 16 KB

  short8 ak[2][2];
#pragma unroll
  for (int s = 0; s < 2; ++s)
#pragma unroll
    for (int dh = 0; dh < 2; ++dh)
      ak[s][dh] = *(const short8*)(KB + ((size_t)b*SS + kb0 + 32*w + 16*s + r15)*DD + 32*dh + 8*g);

  const int q0g = qch * QCH;
#define PA_STAGE(tt, buf) do {                                              \
    _Pragma("unroll")                                                       \
    for (int j = 0; j < 2; ++j) {                                           \
      const int row = 16*w + 8*j + (lane >> 3);                             \
      const char* gsrc = (const char*)(QB + ((size_t)b*SS + q0g + (tt)*64 + row)*DD) \
                         + 16*((lane & 7) ^ (row & 7));                     \
      gload16(gsrc, qbuf[buf] + (16*w + 8*j)*128);                          \
    }                                                                       \
  } while (0)

  PA_STAGE(0, 0);

  float z[8];
#pragma unroll
  for (int i = 0; i < 8; ++i) z[i] = 0.f;

#pragma unroll 1
  for (int tt = 0; tt < NT; ++tt) {
    if (tt < NT-1) {
      PA_STAGE(tt+1, (tt+1)&1);
      WAIT_VM(2);
    } else {
      WAIT_VM(0);
    }
    BAR();
    const char* qb = qbuf[tt & 1];
#pragma unroll
    for (int qt = 0; qt < 4; ++qt) {
      const int qrow = 16*qt + r15;
      const char* base = qb + qrow*128;
      short8 bq0 = *(const short8*)(base + 16*((g    ) ^ (qrow & 7)));
      short8 bq1 = *(const short8*)(base + 16*((4 + g) ^ (qrow & 7)));
#pragma unroll
      for (int s = 0; s < 2; ++s) {
        f32x4 a = {0.f,0.f,0.f,0.f};
        a = MFMA32(ak[s][0], bq0, a);
        a = MFMA32(ak[s][1], bq1, a);
        z[4*s+0] += exp2f(a[0]); z[4*s+1] += exp2f(a[1]);
        z[4*s+2] += exp2f(a[2]); z[4*s+3] += exp2f(a[3]);
      }
    }
    DS_FENCE();
    BAR();
  }
#undef PA_STAGE

#pragma unroll
  for (int m = 1; m < 16; m <<= 1)
#pragma unroll
    for (int i = 0; i < 8; ++i) z[i] += __shfl_xor(z[i], m);
  if (r15 == 0) {
#pragma unroll
    for (int s = 0; s < 2; ++s)
#pragma unroll
      for (int r = 0; r < 4; ++r)
        Zp[((size_t)qch*BB + b)*SS + kb0 + 32*w + 16*s + 4*g + r] = z[4*s+r];
  }
}

// ---------------- P2: VT[b][d][s] = bf16( V[b][s][d] / Z[s] )
__global__ __launch_bounds__(256) void p2_vt(
    const float* __restrict__ v, const float* __restrict__ Zp,
    ushort_t* __restrict__ VT)
{
  const int k0 = blockIdx.x * 64;
  const int b  = blockIdx.y;
  const int t = threadIdx.x;
  __shared__ float vs[64][65];
  __shared__ float izs[64];
  {
    const int row = t >> 2, cq = (t & 3) * 16;
    const float* src = v + ((size_t)b*SS + k0 + row)*DD + cq;
#pragma unroll
    for (int i = 0; i < 4; ++i) {
      float4 x = ((const float4*)src)[i];
      vs[row][cq + 4*i + 0] = x.x; vs[row][cq + 4*i + 1] = x.y;
      vs[row][cq + 4*i + 2] = x.z; vs[row][cq + 4*i + 3] = x.w;
    }
  }
  if (t < 64) {
    float z = 0.f;
#pragma unroll
    for (int c = 0; c < QSPLIT; ++c)
      z += Zp[((size_t)c*BB + b)*SS + k0 + t];
    izs[t] = 1.0f / z;
  }
  __syncthreads();
  const int d = t >> 2, ks = (t & 3) * 16;
  u32* dst = (u32*)VT + (((size_t)b*DD + d)*SS + k0 + ks)/2;
#pragma unroll
  for (int i = 0; i < 8; ++i) {
    float a0 = vs[ks + 2*i    ][d] * izs[ks + 2*i    ];
    float a1 = vs[ks + 2*i + 1][d] * izs[ks + 2*i + 1];
    dst[i] = (u32)f2bf(a0) | ((u32)f2bf(a1) << 16);
  }
}

// ============ PB: attn contribution = exp2(QK'^T) * VT over this block's k-quarter ============
// grid (SS/128, KSPLIT, BB), 256 thr. Block tile: 128 q x 64 k per step (BK=64).
// Wave w: wk=w>>1 selects 32-k half, qs=w&1 selects 64-q half (4 qt each).
// Swapped QK^T gives P[k=32wk+16s+4g+rr][q=r15]; two s-subtiles pack into one
// K=32 A-frag; V B-frag gathered with the SAME per-lane k permutation ->
// P never leaves registers. 32 KB dbuf LDS, counted vmcnt(4), raw barriers.
// MODE 0: atomicAdd into out0.  MODE 1: plain store to partials[ky].
template<int MODE>
__global__ __launch_bounds__(256) void pb_attn(
    const ushort_t* __restrict__ QB, const ushort_t* __restrict__ KB,
    const ushort_t* __restrict__ VT, float* __restrict__ outp)
{
  const int qbase = blockIdx.x * 128;
  const int ky = blockIdx.y;
  const int kbase = ky * (SS / KSPLIT);
  const int b  = blockIdx.z;
  const int t = threadIdx.x, w = t >> 6, lane = t & 63;
  const int g = lane >> 4, r15 = lane & 15;
  const int wk = w >> 1, qs = w & 1;
  const int NT = SS / KSPLIT / 64;    // 16

  __shared__ alignas(16) char smem[32768];   // dbuf: [2][8KB K + 8KB V]

  // Q fragments in registers: this wave's 64 q rows (4 qt of 16)
  short8 aq[4][2];
#pragma unroll
  for (int qt = 0; qt < 4; ++qt)
#pragma unroll
    for (int dh = 0; dh < 2; ++dh)
      aq[qt][dh] = *(const short8*)(QB + ((size_t)b*SS + qbase + 64*qs + 16*qt + r15)*DD + 32*dh + 8*g);

  f32x4 acc[4][4];
#pragma unroll
  for (int qt = 0; qt < 4; ++qt)
#pragma unroll
    for (int dt = 0; dt < 4; ++dt) acc[qt][dt] = (f32x4){0.f,0.f,0.f,0.f};

  // stage tile kt into buf: K 64 rows x 128B + V 64 d-rows x 128B (64 k x 2B)
#define PB_STAGE(kt, buf) do {                                               \
    const int kc = kbase + (kt)*64;                                          \
    _Pragma("unroll")                                                        \
    for (int j = 0; j < 2; ++j) {                                            \
      const int row = 16*w + 8*j + (lane >> 3);                              \
      const char* gk = (const char*)(KB + ((size_t)b*SS + kc + row)*DD)      \
                       + 16*((lane & 7) ^ (row & 7));                        \
      gload16(gk, smem + (buf)*16384 + (16*w + 8*j)*128);                    \
    }                                                                        \
    _Pragma("unroll")                                                        \
    for (int j = 0; j < 2; ++j) {                                            \
      const int row = 16*w + 8*j + (lane >> 3);                              \
      const char* gv = (const char*)(VT + ((size_t)b*DD + row)*SS + kc)      \
                       + 16*((lane & 7) ^ (row & 7));                        \
      gload16(gv, smem + (buf)*16384 + 8192 + (16*w + 8*j)*128);             \
    }                                                                        \
  } while (0)

  PB_STAGE(0, 0);

#pragma unroll 1
  for (int kt = 0; kt < NT; ++kt) {
    if (kt < NT-1) {
      PB_STAGE(kt+1, (kt+1)&1);
      WAIT_VM(4);
    } else {
      WAIT_VM(0);
    }
    BAR();
    const char* kb = smem + (kt&1)*16384;
    const char* vb = kb + 8192;

    // QK^T (swapped: A=K rows 32wk+16s.., B=Q[qt]) -> P[k=32wk+16s+4g+rr][q=r15]
    u32 pku[2][4][2];
#pragma unroll
    for (int s = 0; s < 2; ++s) {
      const int rowA = 32*wk + 16*s + r15;
      const char* base = kb + rowA*128;
      short8 ka0 = *(const short8*)(base + 16*((g    ) ^ (r15 & 7)));
      short8 ka1 = *(const short8*)(base + 16*((4 + g) ^ (r15 & 7)));
#pragma unroll
      for (int qt = 0; qt < 4; ++qt) {
        f32x4 a = {0.f,0.f,0.f,0.f};
        a = MFMA32(ka0, aq[qt][0], a);
        a = MFMA32(ka1, aq[qt][1], a);
        pku[s][qt][0] = pk2(exp2f(a[0]), exp2f(a[1]));
        pku[s][qt][1] = pk2(exp2f(a[2]), exp2f(a[3]));
      }
    }
    // V B-frags with the SAME k permutation: bytes 64wk+8g (+32 for s=1)
    short8 bv[4];
#pragma unroll
    for (int dt = 0; dt < 4; ++dt) {
      const int vrow = 16*dt + r15;
      Pk8 u;
      u.h[0] = *(const u32x2*)(vb + vrow*128 + 16*((4*wk     + (g>>1)) ^ (r15 & 7)) + 8*(g&1));
      u.h[1] = *(const u32x2*)(vb + vrow*128 + 16*((4*wk + 2 + (g>>1)) ^ (r15 & 7)) + 8*(g&1));
      bv[dt] = u.s8;
    }
    // PV: A = P (registers), K=32
#pragma unroll
    for (int qt = 0; qt < 4; ++qt) {
      Pk8 ap;
      ap.u[0] = pku[0][qt][0]; ap.u[1] = pku[0][qt][1];
      ap.u[2] = pku[1][qt][0]; ap.u[3] = pku[1][qt][1];
#pragma unroll
      for (int dt = 0; dt < 4; ++dt)
        acc[qt][dt] = MFMA32(ap.s8, bv[dt], acc[qt][dt]);
    }
    DS_FENCE();
    BAR();
  }
#undef PB_STAGE

  // reduce the two wk halves (same qs) through LDS (32 KB), then wk==0 outputs
  f32x4* red = (f32x4*)smem;   // [2 qs][16][64] = 32 KB
  if (wk == 1) {
#pragma unroll
    for (int qt = 0; qt < 4; ++qt)
#pragma unroll
      for (int dt = 0; dt < 4; ++dt) red[(qs*16 + qt*4 + dt)*64 + lane] = acc[qt][dt];
  }
  __syncthreads();
  if (wk == 0) {
    float* dst = (MODE == 0) ? outp : outp + (size_t)ky * BB * SS * DD;
#pragma unroll
    for (int qt = 0; qt < 4; ++qt)
#pragma unroll
      for (int dt = 0; dt < 4; ++dt) {
        f32x4 s = acc[qt][dt] + red[(qs*16 + qt*4 + dt)*64 + lane];
#pragma unroll
        for (int rr = 0; rr < 4; ++rr) {
          const size_t idx = ((size_t)b*SS + qbase + 64*qs + 16*qt + 4*g + rr)*DD + 16*dt + r15;
          if (MODE == 0) atomicAdd(&outp[idx], s[rr]);
          else           dst[idx] = s[rr];
        }
      }
  }
}

// ---------------- K4F (atomic fallback): colsum of exp(attn) -> z2
__global__ __launch_bounds__(256) void k4f(
    const float* __restrict__ attn, float* __restrict__ z2)
{
  const int b = blockIdx.x;
  const int q0 = blockIdx.y * 32;
  const int t = threadIdx.x;
  const int d = t & 63, rg = t >> 6;
  float ze = 0.f;
#pragma unroll
  for (int i = 0; i < 8; ++i) {
    float a = attn[((size_t)b*SS + q0 + 4*i + rg)*DD + d];
    ze += __expf(a);
  }
  __shared__ float red[4][64];
  red[rg][d] = ze;
  __syncthreads();
  if (t < 64)
    atomicAdd(&z2[b*DD + t], red[0][t] + red[1][t] + red[2][t] + red[3][t]);
}

// ---------------- K5 (partials path): attn = sum partials -> out0, + exp colsum -> z2
__global__ __launch_bounds__(256) void k5_comb(
    const float* __restrict__ parts, float* __restrict__ out0, float* __restrict__ z2)
{
  const int b = blockIdx.x;
  const int q0 = blockIdx.y * 32;
  const int t = threadIdx.x;
  const int d = t & 63, rg = t >> 6;
  const size_t N = (size_t)BB * SS * DD;
  float ze = 0.f;
#pragma unroll
  for (int i = 0; i < 8; ++i) {
    const size_t idx = ((size_t)b*SS + q0 + 4*i + rg)*DD + d;
    float a = parts[idx] + parts[N + idx] + parts[2*N + idx] + parts[3*N + idx];
    out0[idx] = a;
    ze += __expf(a);
  }
  __shared__ float red[4][64];
  red[rg][d] = ze;
  __syncthreads();
  if (t < 64)
    atomicAdd(&z2[b*DD + t], red[0][t] + red[1][t] + red[2][t] + red[3][t]);
}

// ---------------- K6: attn_w = exp(attn) / z2
__global__ __launch_bounds__(256) void k6w(
    const float* __restrict__ attn, const float* __restrict__ z2,
    float* __restrict__ out1)
{
  const size_t i = (size_t)blockIdx.x * 256 + threadIdx.x;
  const int b = (int)(i >> 18);        // SS*DD = 262144
  const int d = (int)(i & 63);
  out1[i] = __expf(attn[i]) / z2[b*DD + d];
}

extern "C" void kernel_launch(void* const* d_in, const int* in_sizes, int n_in,
                              void* d_out, int out_size, void* d_ws, size_t ws_size,
                              hipStream_t stream) {
  const float* q = (const float*)d_in[0];
  const float* k = (const float*)d_in[1];
  const float* v = (const float*)d_in[2];
  float* out0 = (float*)d_out;
  float* out1 = out0 + (size_t)BB * SS * DD;

  // bf16 Q/K scratch lives in the out1 region (overwritten by k6w at the end).
  ushort_t* QB = (ushort_t*)out1;                 // 2 MB
  ushort_t* KB = QB + (size_t)BB * SS * DD;       // 2 MB

  char* ws = (char*)d_ws;
  ushort_t* VT = (ushort_t*)ws;                               // 2 MB bf16
  float* Zp = (float*)(ws + (size_t)BB*DD*SS*2);              // 256 KB
  float* z2 = Zp + (size_t)QSPLIT * BB * SS;                  // 1 KB
  float* parts = z2 + 256;                                    // 16 MB (if available)

  const size_t need = (size_t)BB*DD*SS*2 + (size_t)QSPLIT*BB*SS*4 + 1024
                    + (size_t)KSPLIT*BB*SS*DD*4;
  const bool use_parts = (ws_size >= need);

  hipLaunchKernelGGL(p0_convert, dim3(BB*SS*DD/4/256), dim3(256), 0, stream, q, k, QB, KB, out0, z2);
  hipLaunchKernelGGL(pa_colsum, dim3(SS/128, QSPLIT, BB), dim3(256), 0, stream, QB, KB, Zp);
  hipLaunchKernelGGL(p2_vt, dim3(SS/64, BB), dim3(256), 0, stream, v, Zp, VT);
  if (use_parts) {
    pb_attn<1><<<dim3(SS/128, KSPLIT, BB), dim3(256), 0, stream>>>(QB, KB, VT, parts);
    hipLaunchKernelGGL(k5_comb, dim3(BB, SS/32), dim3(256), 0, stream, parts, out0, z2);
  } else {
    pb_attn<0><<<dim3(SS/128, KSPLIT, BB), dim3(256), 0, stream>>>(QB, KB, VT, out0);
    hipLaunchKernelGGL(k4f, dim3(BB, SS/32), dim3(256), 0, stream, out0, z2);
  }
  hipLaunchKernelGGL(k6w, dim3(BB*SS*DD/256), dim3(256), 0, stream, out0, z2, out1);
}